// Round 1
// baseline (158.798 us; speedup 1.0000x reference)
//
#include <hip/hip_runtime.h>

// Histogram2D: x (16, 131072, 2) f32 in [0,1) -> counts (16, 100, 100) f32, normalized.
// Strategy: LDS-privatized per-(batch,partial) histogram + global atomic flush into
// d_out (used as raw accumulator), then per-batch block-reduce + in-place normalize.

#define BINS     100
#define NBINS2   (BINS * BINS)     // 10000
#define NPOINTS  131072
#define NBATCH   16
#define PPB      32                // partial blocks per batch
#define CHUNK    (NPOINTS / PPB)   // 4096 points per block
#define THREADS  1024

__global__ __launch_bounds__(THREADS) void hist_accum_kernel(
    const float* __restrict__ x, float* __restrict__ out)
{
    __shared__ float lhist[NBINS2];
    for (int i = threadIdx.x; i < NBINS2; i += THREADS) lhist[i] = 0.0f;
    __syncthreads();

    const int b  = blockIdx.x / PPB;
    const int pb = blockIdx.x % PPB;
    // 4096 points = 8192 floats = 2048 float4 per block
    const float4* __restrict__ xp = reinterpret_cast<const float4*>(
        x + (size_t)b * (NPOINTS * 2) + (size_t)pb * (CHUNK * 2));

    #pragma unroll
    for (int k = 0; k < (CHUNK / 2) / THREADS; ++k) {
        const float4 p = xp[threadIdx.x + k * THREADS];
        #pragma unroll
        for (int pt = 0; pt < 2; ++pt) {
            const float x0 = pt ? p.z : p.x;
            const float x1 = pt ? p.w : p.y;
            // bin index: floor(x / DELTA) with IEEE float32 division (matches numpy)
            int i0 = (int)floorf(__fdiv_rn(x0, 0.01f));
            int i1 = (int)floorf(__fdiv_rn(x1, 0.01f));
            i0 = min(max(i0, 0), BINS - 1);
            i1 = min(max(i1, 0), BINS - 1);
            const int b0 = i0 - 2, b1 = i1 - 2;
            float d0[5], d1[5];
            #pragma unroll
            for (int o = 0; o < 5; ++o) {
                const int n0 = b0 + o;
                const int n1 = b1 + o;
                // center = DELTA * (n + 0.5), single rounding (no FMA contraction)
                const float c0 = __fmul_rn(0.01f, (float)n0 + 0.5f);
                const float c1 = __fmul_rn(0.01f, (float)n1 + 0.5f);
                d0[o] = (n0 >= 0 && n0 < BINS) ? fabsf(__fsub_rn(x0, c0)) : 1e9f;
                d1[o] = (n1 >= 0 && n1 < BINS) ? fabsf(__fsub_rn(x1, c1)) : 1e9f;
            }
            #pragma unroll
            for (int i = 0; i < 5; ++i) {
                const float di = d0[i];
                const int rowoff = (b0 + i) * BINS + b1;
                #pragma unroll
                for (int j = 0; j < 5; ++j) {
                    // w = relu(DELTA - 0.5*(d0+d1)); 0.5*s is exact so rounding matches ref
                    const float s = __fadd_rn(di, d1[j]);
                    const float w = __fsub_rn(0.01f, __fmul_rn(0.5f, s));
                    if (w > 0.0f) atomicAdd(&lhist[rowoff + j], w);
                }
            }
        }
    }
    __syncthreads();

    float* __restrict__ ob = out + (size_t)b * NBINS2;
    for (int i = threadIdx.x; i < NBINS2; i += THREADS) {
        const float v = lhist[i];
        if (v != 0.0f) unsafeAtomicAdd(&ob[i], v);  // global_atomic_add_f32
    }
}

__global__ __launch_bounds__(1024) void norm_kernel(float* __restrict__ out)
{
    const int b = blockIdx.x;
    float* __restrict__ h = out + (size_t)b * NBINS2;

    float local = 0.0f;
    for (int i = threadIdx.x; i < NBINS2; i += 1024) local += h[i];
    #pragma unroll
    for (int off = 32; off > 0; off >>= 1) local += __shfl_down(local, off, 64);

    __shared__ float wsum[16];
    __shared__ float sden;
    const int wid  = threadIdx.x >> 6;
    const int lane = threadIdx.x & 63;
    if (lane == 0) wsum[wid] = local;
    __syncthreads();
    if (threadIdx.x == 0) {
        float t = 0.0f;
        #pragma unroll
        for (int i = 0; i < 16; ++i) t += wsum[i];
        sden = __fadd_rn(t, 1e-5f);
    }
    __syncthreads();
    const float den = sden;
    for (int i = threadIdx.x; i < NBINS2; i += 1024) h[i] = __fdiv_rn(h[i], den);
}

extern "C" void kernel_launch(void* const* d_in, const int* in_sizes, int n_in,
                              void* d_out, int out_size, void* d_ws, size_t ws_size,
                              hipStream_t stream) {
    (void)in_sizes; (void)n_in; (void)d_ws; (void)ws_size;
    const float* x = (const float*)d_in[0];
    float* out = (float*)d_out;

    // d_out is poisoned before every call -> zero it (memset nodes are graph-capturable)
    hipMemsetAsync(out, 0, (size_t)out_size * sizeof(float), stream);
    hist_accum_kernel<<<NBATCH * PPB, THREADS, 0, stream>>>(x, out);
    norm_kernel<<<NBATCH, 1024, 0, stream>>>(out);
}